// Round 6
// baseline (287.877 us; speedup 1.0000x reference)
//
#include <hip/hip_runtime.h>

namespace {

constexpr int kE  = 1024;
constexpr int kH  = 16;
constexpr int kR  = 256;
constexpr int kHD = 64;
constexpr int kB  = 2;
constexpr int kS  = 2048;
constexpr int kM  = kB * kS;   // 4096

typedef float  floatx4 __attribute__((ext_vector_type(4)));
typedef short  short8  __attribute__((ext_vector_type(8)));
typedef short  short4  __attribute__((ext_vector_type(4)));

__device__ inline short f2bf(float f) {
  union { float f; unsigned u; } x{f};
  unsigned r = x.u + 0x7FFF + ((x.u >> 16) & 1);   // RNE
  return (short)(r >> 16);
}

// pack two floats -> two bf16 (round-half-up) in one v_perm_b32.
__device__ inline unsigned pack2bf(float a, float b) {
#if defined(__HIP_DEVICE_COMPILE__)
  unsigned ua = __float_as_uint(a) + 0x8000u;
  unsigned ub = __float_as_uint(b) + 0x8000u;
  return __builtin_amdgcn_perm(ub, ua, 0x07060302u);  // hi16(b):hi16(a)
#else
  (void)a; (void)b; return 0;
#endif
}

__device__ inline short4 pack4bf(float p0, float p1, float p2, float p3) {
  union { unsigned u[2]; short4 s; } r;
  r.u[0] = pack2bf(p0, p1);
  r.u[1] = pack2bf(p2, p3);
  return r.s;
}

// async global->LDS, 16B per lane. LDS dest = wave-uniform base + lane*16.
__device__ inline void async_copy16(const void* g, void* l) {
  __builtin_amdgcn_global_load_lds(
      (const __attribute__((address_space(1))) unsigned int*)g,
      (__attribute__((address_space(3))) unsigned int*)l,
      16, 0, 0);
}

// 16x16x16 bf16 MFMA. __has_builtin is FALSE on the host pass -> guard.
#if defined(__HIP_DEVICE_COMPILE__)
  #if __has_builtin(__builtin_amdgcn_mfma_f32_16x16x16bf16_1k)
    #define MFMA16(a, b, c) __builtin_amdgcn_mfma_f32_16x16x16bf16_1k(a, b, c, 0, 0, 0)
  #elif __has_builtin(__builtin_amdgcn_mfma_f32_16x16x16_bf16)
    #define MFMA16(a, b, c) __builtin_amdgcn_mfma_f32_16x16x16_bf16(a, b, c, 0, 0, 0)
  #else
    #error "no 16x16x16 bf16 MFMA builtin on device"
  #endif
#else
  #define MFMA16(a, b, c) (c)
#endif

// ---------------------------------------------------------------------------
// Weight prep: fp32 W (K,N) row-major -> bf16 W^T (N,K) row-major.
// ---------------------------------------------------------------------------
struct PrepArgs { const float* src[8]; short* dst[8]; };

__global__ __launch_bounds__(256) void prep_weights(PrepArgs pa) {
  const int id = blockIdx.y;
  const bool lo = (id & 1) == 0;
  const int K = lo ? 1024 : 256;
  const int N = lo ? 256 : 1024;
  const int tiles_k = K >> 6;
  const int k0 = (blockIdx.x % tiles_k) * 64;
  const int n0 = (blockIdx.x / tiles_k) * 64;
  const float* src = pa.src[id];
  short* dst = pa.dst[id];

  __shared__ float tile[64][68];
  const int t  = threadIdx.x;
  const int c4 = (t & 15) * 4;
  const int r  = t >> 4;

#pragma unroll
  for (int i = 0; i < 4; ++i) {
    const int rk = r + i * 16;
    *(float4*)&tile[rk][c4] = *(const float4*)&src[(size_t)(k0 + rk) * N + n0 + c4];
  }
  __syncthreads();
#pragma unroll
  for (int i = 0; i < 4; ++i) {
    const int rn = r + i * 16;
    short4 o = { f2bf(tile[c4 + 0][rn]), f2bf(tile[c4 + 1][rn]),
                 f2bf(tile[c4 + 2][rn]), f2bf(tile[c4 + 3][rn]) };
    *(short4*)&dst[(size_t)(n0 + rn) * K + k0 + c4] = o;
  }
}

// ---------------------------------------------------------------------------
// Double-buffered bf16 MFMA GEMM, NT: C[M,N] = A[M,K] @ Bt[N,K]^T + bias.
// BK=64, one barrier per k-iter; staging of next tile overlaps compute.
// AF32: A is fp32, converted in-register during staging, written to a
//       XOR-swizzled LDS layout (conflict-free fragment reads).
// else: A bf16 staged via global_load_lds (linear layout).
// MODE 0: bf16 row-major out. MODE 1: attention layouts (z<2 Q/K head-major
// (bh,s,d); z==2 V^T (bh,d,s)). MODE 2: fp32 row-major out.
// ---------------------------------------------------------------------------
struct GemmArgs {
  const void* A[3]; const short* Bt[3]; const float* bias[3];
  void* C[3]; float scale[3];
};

template <int N, int K, int BM, int BN, int MODE, bool AF32>
__global__ __launch_bounds__(256) void gemm_k(GemmArgs args) {
  static_assert(!AF32 || BM == 64, "AF32 staging assumes BM=64");
  constexpr int TILES_N = N / BN;
  constexpr int WTM = BM / 2, WTN = BN / 2;
  constexpr int FI = WTM / 16, FJ = WTN / 16;
  constexpr int BR = (BN * 128) / 4096;   // B staging rounds (BK=64 -> 128B/row)
  constexpr int AR = (BM * 128) / 4096;

  const int z = blockIdx.y;
  const int row0 = (blockIdx.x / TILES_N) * BM;
  const int col0 = (blockIdx.x % TILES_N) * BN;
  const short* Bt = args.Bt[z];
  const float* bias = args.bias[z];
  const float scale = args.scale[z];
  const float* Af = (const float*)args.A[z];
  const short* Ah = (const short*)args.A[z];

  __shared__ short As[2][BM * 64];
  __shared__ short Bs[2][BN * 64];

  const int t    = threadIdx.x;
  const int wave = t >> 6;
  const int lane = t & 63;
  const int lq   = lane & 15;
  const int quad = lane >> 4;
  const int wm0  = (wave >> 1) * WTM;
  const int wn0  = (wave & 1) * WTN;

  auto stageB = [&](int buf, int kk) {
#pragma unroll
    for (int r = 0; r < BR; ++r)
      async_copy16(Bt + (size_t)(col0 + r * 32 + wave * 8 + (lane >> 3)) * K + kk + (lane & 7) * 8,
                   (char*)Bs[buf] + r * 4096 + wave * 1024);
  };
  auto stageA = [&](int buf, int kk) {
    if constexpr (AF32) {
#pragma unroll
      for (int r = 0; r < 2; ++r) {
        const int i = r * 256 + t;
        const int row = i >> 3, blk = i & 7;
        const float* src = Af + (size_t)(row0 + row) * K + kk + blk * 8;
        float4 x = *(const float4*)src;
        float4 y = *(const float4*)(src + 4);
        unsigned* dst = (unsigned*)&As[buf][row * 64 + (blk ^ (row & 7)) * 8];
        dst[0] = pack2bf(x.x, x.y);
        dst[1] = pack2bf(x.z, x.w);
        dst[2] = pack2bf(y.x, y.y);
        dst[3] = pack2bf(y.z, y.w);
      }
    } else {
#pragma unroll
      for (int r = 0; r < AR; ++r)
        async_copy16(Ah + (size_t)(row0 + r * 32 + wave * 8 + (lane >> 3)) * K + kk + (lane & 7) * 8,
                     (char*)As[buf] + r * 4096 + wave * 1024);
    }
  };

  floatx4 acc[FI][FJ] = {};
  stageB(0, 0);
  stageA(0, 0);
  int buf = 0;

  for (int kk = 0; kk < K; kk += 64) {
    __syncthreads();                       // staging for `buf` complete
    if (kk + 64 < K) { stageB(buf ^ 1, kk + 64); stageA(buf ^ 1, kk + 64); }

#pragma unroll
    for (int ks = 0; ks < 2; ++ks) {
      short8 af[FI], bf[FJ];
#pragma unroll
      for (int i = 0; i < FI; ++i) {
        int blk = 4 * ks + quad;
        if constexpr (AF32) blk ^= (lq & 7);
        af[i] = *(const short8*)&As[buf][(wm0 + i * 16 + lq) * 64 + blk * 8];
      }
#pragma unroll
      for (int j = 0; j < FJ; ++j)
        bf[j] = *(const short8*)&Bs[buf][(wn0 + j * 16 + lq) * 64 + ks * 32 + quad * 8];
#pragma unroll
      for (int i = 0; i < FI; ++i)
#pragma unroll
        for (int j = 0; j < FJ; ++j)
          acc[i][j] = __builtin_amdgcn_mfma_f32_16x16x32_bf16(af[i], bf[j], acc[i][j], 0, 0, 0);
    }
    buf ^= 1;
  }

#pragma unroll
  for (int i = 0; i < FI; ++i) {
    const int rbase = row0 + wm0 + i * 16 + quad * 4;
#pragma unroll
    for (int j = 0; j < FJ; ++j) {
      const int col = col0 + wn0 + j * 16 + lq;
      const float bj = bias[col];
      if (MODE == 2) {
        float* C = (float*)args.C[z];
#pragma unroll
        for (int r = 0; r < 4; ++r)
          C[(size_t)(rbase + r) * N + col] = (acc[i][j][r] + bj) * scale;
      } else if (MODE == 1) {
        short* C = (short*)args.C[z];
        const int h = col >> 6, d = col & 63;
        const int b = rbase >> 11, s = rbase & 2047;
        if (z == 2) {
          short4 o = pack4bf(acc[i][j][0] + bj, acc[i][j][1] + bj,
                             acc[i][j][2] + bj, acc[i][j][3] + bj);
          *(short4*)&C[((size_t)((b * 16 + h) * 64 + d)) * 2048 + s] = o;
        } else {
#pragma unroll
          for (int r = 0; r < 4; ++r)
            C[((size_t)((b * 16 + h) * 2048 + s + r)) * 64 + d] =
                f2bf((acc[i][j][r] + bj) * scale);
        }
      } else {
        short* C = (short*)args.C[z];
#pragma unroll
        for (int r = 0; r < 4; ++r)
          C[(size_t)(rbase + r) * N + col] = f2bf((acc[i][j][r] + bj) * scale);
      }
    }
  }
}

// ---------------------------------------------------------------------------
// Flash attention, bf16 MFMA. 4 waves, 64 q-rows/block, 64-key chunks.
// LDS: [64][64] shorts, XOR-8-block swizzle (phys_blk = blk ^ (row&7)) ->
// conflict-free b128 K-reads, b64 V-reads, and b128 staging writes.
// Double-buffered, ONE barrier per chunk; next chunk's global loads issued
// right after the barrier so they fly during compute.
// Scores arrive pre-scaled by 0.125*log2(e) -> softmax in exp2 domain.
// P stays in registers (S^T C-layout == 16x16x16 B-layout).
// ---------------------------------------------------------------------------
__global__ __launch_bounds__(256) void attn_mfma(
    const short* __restrict__ Qp, const short* __restrict__ Kp,
    const short* __restrict__ Vtp, short* __restrict__ O)
{
  __shared__ short Ks[2][64 * 64];
  __shared__ short Vs[2][64 * 64];

  const int t    = threadIdx.x;
  const int wave = t >> 6;
  const int lane = t & 63;
  const int lq   = lane & 15;
  const int quad = lane >> 4;

  const int q0 = blockIdx.x * 64;
  const int bh = blockIdx.y;
  const int b  = bh >> 4;
  const int h  = bh & 15;

  // Q fragments (head-major (bh,s,d)), pre-scaled by 0.125*log2e in the GEMM
  const short* qrow = Qp + ((size_t)bh * kS + q0 + wave * 16 + lq) * 64;
  short8 qf0 = *(const short8*)(qrow + quad * 8);
  short8 qf1 = *(const short8*)(qrow + 32 + quad * 8);

  const short* Kbase = Kp  + (size_t)bh * kS * 64;   // (s, d)
  const short* Vbase = Vtp + (size_t)bh * 64 * kS;   // (d, s)

  // staging: rows srow, srow+8 (same xor phase), 8 lanes * 16B per row
  const int srow  = wave * 16 + (lane >> 3);
  const int sblk  = lane & 7;
  const int swr   = srow * 64 + (sblk ^ (srow & 7)) * 8;   // shorts
  const short* kst = Kbase + (size_t)srow * 64 + sblk * 8;
  const short* vst = Vbase + (size_t)srow * kS + sblk * 8;

  floatx4 Oacc[4] = {};
  float m = -1e30f;
  float l = 0.f;

  short8 gk0 = *(const short8*)(kst);
  short8 gk1 = *(const short8*)(kst + 8 * 64);
  short8 gv0 = *(const short8*)(vst);
  short8 gv1 = *(const short8*)(vst + 8 * kS);

  int buf = 0;
  for (int kc = 0; kc < kS; kc += 64) {
    *(short8*)&Ks[buf][swr]       = gk0;
    *(short8*)&Ks[buf][swr + 512] = gk1;   // row+8: +8*64 shorts
    *(short8*)&Vs[buf][swr]       = gv0;
    *(short8*)&Vs[buf][swr + 512] = gv1;
    __syncthreads();

    if (kc + 64 < kS) {                    // issue next loads; fly during compute
      gk0 = *(const short8*)(kst + (size_t)(kc + 64) * 64);
      gk1 = *(const short8*)(kst + (size_t)(kc + 64) * 64 + 8 * 64);
      gv0 = *(const short8*)(vst + kc + 64);
      gv1 = *(const short8*)(vst + kc + 64 + 8 * kS);
    }

    // ---- scores: S^T tiles (key16 x q16), A = K rows from swizzled LDS ----
    floatx4 Sc[4];
#pragma unroll
    for (int tt = 0; tt < 4; ++tt) {
      const int krow = (tt * 16 + lq) * 64;
      const int xr   = lq & 7;
      short8 a0 = *(const short8*)&Ks[buf][krow + (quad ^ xr) * 8];
      short8 a1 = *(const short8*)&Ks[buf][krow + ((4 + quad) ^ xr) * 8];
      floatx4 c = {};
      c = __builtin_amdgcn_mfma_f32_16x16x32_bf16(a0, qf0, c, 0, 0, 0);
      c = __builtin_amdgcn_mfma_f32_16x16x32_bf16(a1, qf1, c, 0, 0, 0);
      Sc[tt] = c;
    }

    // ---- online softmax (exp2 domain) ----
    float mc = -1e30f;
#pragma unroll
    for (int tt = 0; tt < 4; ++tt)
#pragma unroll
      for (int r = 0; r < 4; ++r) mc = fmaxf(mc, Sc[tt][r]);
    mc = fmaxf(mc, __shfl_xor(mc, 16, 64));
    mc = fmaxf(mc, __shfl_xor(mc, 32, 64));
    if (mc > m) {                          // rescale only when max moves
      const float alpha = exp2f(m - mc);
      m = mc;
      l *= alpha;
#pragma unroll
      for (int dt = 0; dt < 4; ++dt)
#pragma unroll
        for (int r = 0; r < 4; ++r) Oacc[dt][r] *= alpha;
    }

    float ls = 0.f;
    short4 pf[4];
#pragma unroll
    for (int tt = 0; tt < 4; ++tt) {
      float p0 = exp2f(Sc[tt][0] - m);
      float p1 = exp2f(Sc[tt][1] - m);
      float p2 = exp2f(Sc[tt][2] - m);
      float p3 = exp2f(Sc[tt][3] - m);
      ls += (p0 + p1) + (p2 + p3);
      pf[tt] = pack4bf(p0, p1, p2, p3);
    }
    l += ls;

    // ---- PV: O^T += V^T @ P^T, A = V^T rows from swizzled LDS ----
#pragma unroll
    for (int dt = 0; dt < 4; ++dt) {
      const int vrow = (dt * 16 + lq) * 64;
      const int xr   = lq & 7;
#pragma unroll
      for (int tt = 0; tt < 4; ++tt) {
        short4 vf = *(const short4*)
            &Vs[buf][vrow + ((2 * tt + (quad >> 1)) ^ xr) * 8 + (quad & 1) * 4];
        Oacc[dt] = MFMA16(vf, pf[tt], Oacc[dt]);
      }
    }
    buf ^= 1;
  }

  // ---- epilogue ----
  l += __shfl_xor(l, 16, 64);
  l += __shfl_xor(l, 32, 64);
  const float inv = 1.f / l;

  short* orow = O + ((size_t)(b * kS + q0 + wave * 16 + lq)) * kE + h * kHD;
#pragma unroll
  for (int dt = 0; dt < 4; ++dt) {
    short4 o = pack4bf(Oacc[dt][0] * inv, Oacc[dt][1] * inv,
                       Oacc[dt][2] * inv, Oacc[dt][3] * inv);
    *(short4*)&orow[dt * 16 + quad * 4] = o;
  }
}

}  // namespace

extern "C" void kernel_launch(void* const* d_in, const int* in_sizes, int n_in,
                              void* d_out, int out_size, void* d_ws, size_t ws_size,
                              hipStream_t stream) {
  // ---- workspace layout (bf16 shorts) ----
  short* ws = (short*)d_ws;
  short* Tq  = ws;                         // 4096*256 each
  short* Tk  = Tq  + (size_t)kM * kR;
  short* Tv  = Tk  + (size_t)kM * kR;
  short* Qh  = Tv  + (size_t)kM * kR;      // head-major (bh, s, d)
  short* Kh  = Qh  + (size_t)kM * kE;
  short* Vth = Kh  + (size_t)kM * kE;      // (bh, d, s)
  short* Ab  = Vth + (size_t)kM * kE;      // attn out bf16 (b, s, E)
  short* To  = Ab  + (size_t)kM * kE;
  short* Wt  = To  + (size_t)kM * kR;      // 8 x (1024*256)

  short* WtArr[8];
  for (int i = 0; i < 8; ++i) WtArr[i] = Wt + (size_t)i * (kE * kR);

  constexpr float kQScale = 0.125f * 1.44269504088896341f;  // exp2-domain

  // ---- 1. weight transpose+convert ----
  PrepArgs pa;
  const int widx[8] = {3, 5, 7, 9, 11, 13, 15, 17};
  for (int i = 0; i < 8; ++i) { pa.src[i] = (const float*)d_in[widx[i]]; pa.dst[i] = WtArr[i]; }
  prep_weights<<<dim3(64, 8), dim3(256), 0, stream>>>(pa);

  // ---- 2. qkv lo GEMMs (fp32 A, fused convert) ----
  {
    GemmArgs ga;
    ga.A[0] = d_in[0]; ga.A[1] = d_in[1]; ga.A[2] = d_in[2];
    ga.Bt[0] = WtArr[0]; ga.Bt[1] = WtArr[2]; ga.Bt[2] = WtArr[4];
    ga.bias[0] = (const float*)d_in[4]; ga.bias[1] = (const float*)d_in[8]; ga.bias[2] = (const float*)d_in[12];
    ga.C[0] = Tq; ga.C[1] = Tk; ga.C[2] = Tv;
    ga.scale[0] = ga.scale[1] = ga.scale[2] = 1.f;
    gemm_k<kR, kE, 64, 64, 0, true><<<dim3((kM / 64) * (kR / 64), 3), dim3(256), 0, stream>>>(ga);
  }

  // ---- 3. qkv hi GEMMs -> attention layouts ----
  {
    GemmArgs ga;
    ga.A[0] = Tq; ga.A[1] = Tk; ga.A[2] = Tv;
    ga.Bt[0] = WtArr[1]; ga.Bt[1] = WtArr[3]; ga.Bt[2] = WtArr[5];
    ga.bias[0] = (const float*)d_in[6]; ga.bias[1] = (const float*)d_in[10]; ga.bias[2] = (const float*)d_in[14];
    ga.C[0] = Qh; ga.C[1] = Kh; ga.C[2] = Vth;
    ga.scale[0] = kQScale; ga.scale[1] = 1.f; ga.scale[2] = 1.f;
    gemm_k<kE, kR, 64, 128, 1, false><<<dim3((kM / 64) * (kE / 128), 3), dim3(256), 0, stream>>>(ga);
  }

  // ---- 4. attention ----
  attn_mfma<<<dim3(kS / 64, kB * kH), dim3(256), 0, stream>>>(Qh, Kh, Vth, Ab);

  // ---- 5. output projection lo (bf16 A) ----
  {
    GemmArgs ga;
    ga.A[0] = Ab; ga.Bt[0] = WtArr[6];
    ga.bias[0] = (const float*)d_in[16];
    ga.C[0] = To; ga.scale[0] = 1.f;
    gemm_k<kR, kE, 64, 64, 0, false><<<dim3((kM / 64) * (kR / 64), 1), dim3(256), 0, stream>>>(ga);
  }
  // ---- 6. output projection hi -> fp32 d_out ----
  {
    GemmArgs ga;
    ga.A[0] = To; ga.Bt[0] = WtArr[7];
    ga.bias[0] = (const float*)d_in[18];
    ga.C[0] = d_out; ga.scale[0] = 1.f;
    gemm_k<kE, kR, 64, 128, 2, false><<<dim3((kM / 64) * (kE / 128), 1), dim3(256), 0, stream>>>(ga);
  }
}